// Round 10
// baseline (426.086 us; speedup 1.0000x reference)
//
#include <hip/hip_runtime.h>
#include <stdint.h>

#define B_ROWS 16384
#define IN_DIM 1024
#define H_DIM  1024
#define KDIM   2048   // I + H
#define NDIM   4096   // 4*H
#define NT     64     // K / BK, BK = 32
#define LN_EPSF 1e-5f

typedef unsigned short u16;
typedef float  f32x4  __attribute__((ext_vector_type(4)));
typedef float  fv4    __attribute__((ext_vector_type(4)));
typedef __bf16 bf16x8 __attribute__((ext_vector_type(8)));
typedef u16    u16x4  __attribute__((ext_vector_type(4)));
typedef u16    u16x8  __attribute__((ext_vector_type(8)));

__device__ __forceinline__ u16 f2bf(float f) {
  unsigned u = __float_as_uint(f);
  u += 0x7FFFu + ((u >> 16) & 1u);   // RNE
  return (u16)(u >> 16);
}
__device__ __forceinline__ float bf2f(u16 s) {
  return __uint_as_float(((unsigned)s) << 16);
}

#define GLOAD_LDS16(gp, lp) __builtin_amdgcn_global_load_lds( \
    (__attribute__((address_space(1))) void*)(gp),            \
    (__attribute__((address_space(3))) void*)(lp), 16, 0, 0)

// ---------------- cast kernels ----------------
__global__ __launch_bounds__(256) void cast_concat(
    const float* __restrict__ x, const float* __restrict__ h,
    u16* __restrict__ cat) {
  int idx = blockIdx.x * 256 + threadIdx.x;
  long base = (long)idx * 8;
  int  c = (int)(base & (KDIM - 1));
  long b = base >> 11;
  const float* src = (c < IN_DIM) ? (x + b * IN_DIM + c)
                                  : (h + b * H_DIM + (c - IN_DIM));
  fv4 v0 = *(const fv4*)(src);
  fv4 v1 = *(const fv4*)(src + 4);
  u16x8 o;
  o[0]=f2bf(v0[0]); o[1]=f2bf(v0[1]); o[2]=f2bf(v0[2]); o[3]=f2bf(v0[3]);
  o[4]=f2bf(v1[0]); o[5]=f2bf(v1[1]); o[6]=f2bf(v1[2]); o[7]=f2bf(v1[3]);
  *(u16x8*)(cat + base) = o;
}

__global__ __launch_bounds__(256) void cast_plain(
    const float* __restrict__ w, u16* __restrict__ wb) {
  int idx = blockIdx.x * 256 + threadIdx.x;
  long base = (long)idx * 8;
  fv4 v0 = *(const fv4*)(w + base);
  fv4 v1 = *(const fv4*)(w + base + 4);
  u16x8 o;
  o[0]=f2bf(v0[0]); o[1]=f2bf(v0[1]); o[2]=f2bf(v0[2]); o[3]=f2bf(v0[3]);
  o[4]=f2bf(v1[0]); o[5]=f2bf(v1[1]); o[6]=f2bf(v1[2]); o[7]=f2bf(v1[3]);
  *(u16x8*)(wb + base) = o;
}

// ---------------- GEMM: C[M][N] = A[M][K] * B[N][K]^T ----------------
// R10 occupancy-first: 256x128 tile, BK=32, 8 waves x (64x64) wave-tiles,
// 2-deep LDS ring (48 KiB) + <=128 reg/wave -> 2 blocks (16 waves) per CU.
// Simple m97-style body: stage(t+1) -> 8 ds_read(t) -> 16 MFMA -> vmcnt(0)
// -> barrier. Cross-BLOCK wave overlap hides the drain (m114 mechanism).
// T2 chunk swizzle + col-fast XCD walk retained.

__global__ __launch_bounds__(512, 4) void gemm_bt(
    const u16* __restrict__ A,   // [B_ROWS][KDIM]
    const u16* __restrict__ Bw,  // [NDIM][KDIM]
    u16* __restrict__ C) {       // [B_ROWS][NDIM] bf16
  __shared__ u16 As[2][8192];    // 2 stages x [256 rows][32 k] = 32 KB
  __shared__ u16 Bs[2][4096];    // 2 stages x [128 rows][32 k] = 16 KB

  const int tid  = threadIdx.x;
  const int lane = tid & 63;
  const int wave = tid >> 6;     // 0..7
  const int wm   = wave >> 1;    // 0..3  (64-row slice)
  const int wn   = wave & 1;     // 0..1  (64-col slice)
  const int r    = lane & 15;
  const int g    = lane >> 4;    // 0..3

  // col-fast XCD walk: 2048 blocks = 64 m-panels x 32 n-panels.
  // XCD x owns m-panels x*8..x*8+7; within XCD, n-panel is the fast index.
  const int bid = blockIdx.x;
  const int xcd = bid & 7;
  const int k_  = bid >> 3;            // 0..255
  const int row0 = (xcd * 8 + (k_ >> 5)) * 256;
  const int col0 = (k_ & 31) * 128;

  // staging with pre-swizzled global source: phys chunk c holds logical
  // chunk c ^ ((c>>3)&7). A: chunks tid and tid+512; B: chunk tid.
  const int tid2 = tid ^ ((tid >> 3) & 7);
  const u16* gA0 = A  + (size_t)(row0 + (tid2 >> 2)) * KDIM + (tid2 & 3) * 8;
  const u16* gA1 = gA0 + (size_t)128 * KDIM;
  const u16* gB0 = Bw + (size_t)(col0 + (tid2 >> 2)) * KDIM + (tid2 & 3) * 8;

  // fragment LDS offsets (u16 units), read-side swizzle XOR (bits [5:3])
  const int rswz   = ((r >> 1) & 7) << 3;
  const int base_a = (((wm * 64 + r) * 32) + g * 8) ^ rswz;
  const int base_b = (((wn * 64 + r) * 32) + g * 8) ^ rswz;

  f32x4 acc[4][4] = {};

  // ---- prologue: stage tile 0; drain; barrier ----
  GLOAD_LDS16(gA0, &As[0][tid * 8]);
  GLOAD_LDS16(gA1, &As[0][tid * 8 + 4096]);
  GLOAD_LDS16(gB0, &Bs[0][tid * 8]);
  asm volatile("s_waitcnt vmcnt(0)" ::: "memory");
  __builtin_amdgcn_s_barrier();

  for (int t = 0; t < NT; ++t) {
    const u16* __restrict__ ab = &As[t & 1][0];
    const u16* __restrict__ bb = &Bs[t & 1][0];
    u16* __restrict__ sa = &As[(t + 1) & 1][0];
    u16* __restrict__ sb = &Bs[(t + 1) & 1][0];

    if (t + 1 < NT) {
      const size_t tso = (size_t)(t + 1) * 32;
      GLOAD_LDS16(gA0 + tso, sa + tid * 8);
      GLOAD_LDS16(gA1 + tso, sa + tid * 8 + 4096);
      GLOAD_LDS16(gB0 + tso, sb + tid * 8);
    }

    bf16x8 fa[4], fb[4];
#pragma unroll
    for (int i = 0; i < 4; ++i) {
      fa[i] = *(const bf16x8*)(ab + base_a + i * 512);
      fb[i] = *(const bf16x8*)(bb + base_b + i * 512);
    }
#pragma unroll
    for (int m = 0; m < 4; ++m)
#pragma unroll
      for (int n = 0; n < 4; ++n)
        acc[m][n] = __builtin_amdgcn_mfma_f32_16x16x32_bf16(
            fa[m], fb[n], acc[m][n], 0, 0, 0);

    asm volatile("s_waitcnt vmcnt(0)" ::: "memory");
    __builtin_amdgcn_s_barrier();
  }

  // ---- epilogue: C/D layout col=lane&15, row=(lane>>4)*4+reg ----
#pragma unroll
  for (int m = 0; m < 4; ++m)
#pragma unroll
    for (int n = 0; n < 4; ++n)
#pragma unroll
      for (int q = 0; q < 4; ++q) {
        const int rr = row0 + wm * 64 + m * 16 + g * 4 + q;
        const int cc = col0 + wn * 64 + n * 16 + r;
        C[(size_t)rr * NDIM + cc] = f2bf(acc[m][n][q]);
      }
}

// ---------------- LN over 4096 + gates + LSTM update ----------------
__global__ __launch_bounds__(256) void ln_gates(
    const u16* __restrict__ t,       // [B_ROWS][NDIM] bf16
    const float* __restrict__ cell,  // [B_ROWS][H]
    const float* __restrict__ gamma, // [4][H]
    const float* __restrict__ beta,  // [4][H]
    float* __restrict__ out) {       // new_out | new_cell
  const int b   = blockIdx.x;
  const int tid = threadIdx.x;
  const int h0  = tid * 4;

  const u16* trow = t + (long)b * NDIM;
  float v[4][4];
#pragma unroll
  for (int gi = 0; gi < 4; ++gi) {
    u16x4 raw = *(const u16x4*)&trow[gi * H_DIM + h0];
#pragma unroll
    for (int j = 0; j < 4; ++j) v[gi][j] = bf2f(raw[j]);
  }

  float s1 = 0.f, s2 = 0.f;
#pragma unroll
  for (int gi = 0; gi < 4; ++gi)
#pragma unroll
    for (int j = 0; j < 4; ++j) { s1 += v[gi][j]; s2 += v[gi][j] * v[gi][j]; }

#pragma unroll
  for (int m = 32; m; m >>= 1) {
    s1 += __shfl_xor(s1, m);
    s2 += __shfl_xor(s2, m);
  }
  __shared__ float red[2][4];
  const int wave = tid >> 6, lane = tid & 63;
  if (lane == 0) { red[0][wave] = s1; red[1][wave] = s2; }
  __syncthreads();
  s1 = red[0][0] + red[0][1] + red[0][2] + red[0][3];
  s2 = red[1][0] + red[1][1] + red[1][2] + red[1][3];

  const float mean  = s1 * (1.f / (float)NDIM);
  const float var   = s2 * (1.f / (float)NDIM) - mean * mean;
  const float scale = rsqrtf(var + LN_EPSF);

  float hd[4][4];
#pragma unroll
  for (int gi = 0; gi < 4; ++gi) {
    fv4 gm = *(const fv4*)&gamma[gi * H_DIM + h0];
    fv4 bt = *(const fv4*)&beta[gi * H_DIM + h0];
#pragma unroll
    for (int j = 0; j < 4; ++j)
      hd[gi][j] = (v[gi][j] - mean) * scale * gm[j] + bt[j];
  }

  fv4 cv = *(const fv4*)&cell[(long)b * H_DIM + h0];
  fv4 no, nc;
#pragma unroll
  for (int j = 0; j < 4; ++j) {
    float fg = 1.f / (1.f + expf(-hd[0][j]));
    float ig = 1.f / (1.f + expf(-hd[1][j]));
    float og = 1.f / (1.f + expf(-hd[2][j]));
    float hc = 0.5f * hd[3][j] * (1.f + erff(hd[3][j] * 0.70710678118654752f));
    float ncell = fg * cv[j] + ig * hc;
    nc[j] = ncell;
    no[j] = og * ncell;
  }
  *(fv4*)&out[(long)b * H_DIM + h0] = no;
  *(fv4*)&out[(long)B_ROWS * H_DIM + (long)b * H_DIM + h0] = nc;
}

// ---------------- launch ----------------
extern "C" void kernel_launch(void* const* d_in, const int* in_sizes, int n_in,
                              void* d_out, int out_size, void* d_ws, size_t ws_size,
                              hipStream_t stream) {
  const float* x     = (const float*)d_in[0];
  const float* h     = (const float*)d_in[1];
  const float* cell  = (const float*)d_in[2];
  const float* W     = (const float*)d_in[3];
  const float* gamma = (const float*)d_in[4];
  const float* beta  = (const float*)d_in[5];
  float* out = (float*)d_out;

  const size_t cat_bytes = (size_t)B_ROWS * KDIM * sizeof(u16);  // 64 MB
  const size_t w_bytes   = (size_t)NDIM * KDIM * sizeof(u16);    // 16 MB
  const size_t t_bytes   = (size_t)B_ROWS * NDIM * sizeof(u16);  // 128 MB
  if (ws_size < cat_bytes + w_bytes + t_bytes) return;

  uint8_t* ws = (uint8_t*)d_ws;
  u16* catb = (u16*)ws;
  u16* Wb   = (u16*)(ws + cat_bytes);
  u16* tbuf = (u16*)(ws + cat_bytes + w_bytes);

  cast_concat<<<(B_ROWS * (long)KDIM / 8) / 256, 256, 0, stream>>>(x, h, catb);
  cast_plain<<<(NDIM * (long)KDIM / 8) / 256, 256, 0, stream>>>(W, Wb);

  gemm_bt<<<dim3(2048), 512, 0, stream>>>(catb, Wb, tbuf);

  ln_gates<<<B_ROWS, 256, 0, stream>>>(tbuf, cell, gamma, beta, out);
}

// Round 11
// 364.742 us; speedup vs baseline: 1.1682x; 1.1682x over previous
//
#include <hip/hip_runtime.h>
#include <stdint.h>

#define B_ROWS 16384
#define IN_DIM 1024
#define H_DIM  1024
#define KDIM   2048   // I + H
#define NDIM   4096   // 4*H
#define LN_EPSF 1e-5f

typedef unsigned short u16;
typedef float  f32x4  __attribute__((ext_vector_type(4)));
typedef float  fv4    __attribute__((ext_vector_type(4)));
typedef __bf16 bf16x8 __attribute__((ext_vector_type(8)));
typedef u16    u16x4  __attribute__((ext_vector_type(4)));
typedef u16    u16x8  __attribute__((ext_vector_type(8)));

__device__ __forceinline__ u16 f2bf(float f) {
  unsigned u = __float_as_uint(f);
  u += 0x7FFFu + ((u >> 16) & 1u);   // RNE
  return (u16)(u >> 16);
}
__device__ __forceinline__ float bf2f(u16 s) {
  return __uint_as_float(((unsigned)s) << 16);
}

#define GLOAD_LDS16(gp, lp) __builtin_amdgcn_global_load_lds( \
    (__attribute__((address_space(1))) void*)(gp),            \
    (__attribute__((address_space(3))) void*)(lp), 16, 0, 0)

// ---------------- cast kernels ----------------
__global__ __launch_bounds__(256) void cast_concat(
    const float* __restrict__ x, const float* __restrict__ h,
    u16* __restrict__ cat) {
  int idx = blockIdx.x * 256 + threadIdx.x;
  long base = (long)idx * 8;
  int  c = (int)(base & (KDIM - 1));
  long b = base >> 11;
  const float* src = (c < IN_DIM) ? (x + b * IN_DIM + c)
                                  : (h + b * H_DIM + (c - IN_DIM));
  fv4 v0 = *(const fv4*)(src);
  fv4 v1 = *(const fv4*)(src + 4);
  u16x8 o;
  o[0]=f2bf(v0[0]); o[1]=f2bf(v0[1]); o[2]=f2bf(v0[2]); o[3]=f2bf(v0[3]);
  o[4]=f2bf(v1[0]); o[5]=f2bf(v1[1]); o[6]=f2bf(v1[2]); o[7]=f2bf(v1[3]);
  *(u16x8*)(cat + base) = o;
}

__global__ __launch_bounds__(256) void cast_plain(
    const float* __restrict__ w, u16* __restrict__ wb) {
  int idx = blockIdx.x * 256 + threadIdx.x;
  long base = (long)idx * 8;
  fv4 v0 = *(const fv4*)(w + base);
  fv4 v1 = *(const fv4*)(w + base + 4);
  u16x8 o;
  o[0]=f2bf(v0[0]); o[1]=f2bf(v0[1]); o[2]=f2bf(v0[2]); o[3]=f2bf(v0[3]);
  o[4]=f2bf(v1[0]); o[5]=f2bf(v1[1]); o[6]=f2bf(v1[2]); o[7]=f2bf(v1[3]);
  *(u16x8*)(wb + base) = o;
}

// ---------------- GEMM: C[M][N] = A[M][K] * B[N][K]^T ----------------
// R11: faithful m201 8-phase port. 256x256 tile, BK=64, 8 waves (2Mx4N),
// per-wave 128x64 output (8m x 4n frags, 2 k-slices). LDS: 2 slots x
// {A 4 pieces, B 4 pieces} of [64 rows][64 k] = 128 KiB. 16 iters x 8
// phases; each phase {ds_read 0/4/8/12 || stage 2 gloads -> barrier ->
// lgkm(0) -> setprio -> 16 MFMA -> setprio -> barrier}; vmcnt(4)@p4,
// vmcnt(6)@p8 (ledger-verified). Chunk swizzle + col-fast XCD walk.

#define STA(S_, P_, T_) GLOAD_LDS16(pA + (size_t)(P_) * 64 * KDIM + (T_) * 64, \
                                    &LA[S_][(P_) * 4096 + tid * 8])
#define STB(S_, P_, T_) GLOAD_LDS16(pB + (size_t)(P_) * 64 * KDIM + (T_) * 64, \
                                    &LB[S_][(P_) * 4096 + tid * 8])

#define RDA(S_, MB_) { const u16* ap = &LA[S_][abase + ((MB_) >> 2) * 4096];  \
  _Pragma("unroll") for (int i_ = 0; i_ < 4; ++i_) {                          \
    a[i_][0] = *(const bf16x8*)(ap + i_ * 1024 + kk0);                        \
    a[i_][1] = *(const bf16x8*)(ap + i_ * 1024 + kk1); } }

#define RDB(S_, V_, NB_) { const u16* bp = &LB[S_][bbase + (NB_) * 1024];     \
  _Pragma("unroll") for (int i_ = 0; i_ < 2; ++i_) {                          \
    V_[i_][0] = *(const bf16x8*)(bp + i_ * 1024 + kk0);                       \
    V_[i_][1] = *(const bf16x8*)(bp + i_ * 1024 + kk1); } }

#define MQ(MB_, NB_, V_)                                                      \
  _Pragma("unroll") for (int m_ = 0; m_ < 4; ++m_)                            \
  _Pragma("unroll") for (int n_ = 0; n_ < 2; ++n_) {                          \
    acc[(MB_) + m_][(NB_) + n_] = __builtin_amdgcn_mfma_f32_16x16x32_bf16(    \
        a[m_][0], V_[n_][0], acc[(MB_) + m_][(NB_) + n_], 0, 0, 0);           \
    acc[(MB_) + m_][(NB_) + n_] = __builtin_amdgcn_mfma_f32_16x16x32_bf16(    \
        a[m_][1], V_[n_][1], acc[(MB_) + m_][(NB_) + n_], 0, 0, 0); }

#define HEAD                                                                  \
  __builtin_amdgcn_sched_barrier(0);                                          \
  __builtin_amdgcn_s_barrier();                                               \
  asm volatile("s_waitcnt lgkmcnt(0)" ::: "memory");                          \
  __builtin_amdgcn_sched_barrier(0);                                          \
  __builtin_amdgcn_s_setprio(1);

#define TAIL                                                                  \
  __builtin_amdgcn_s_setprio(0);                                              \
  __builtin_amdgcn_sched_barrier(0);                                          \
  __builtin_amdgcn_s_barrier();

__global__ __launch_bounds__(512, 2) void gemm_bt(
    const u16* __restrict__ A,   // [B_ROWS][KDIM]
    const u16* __restrict__ Bw,  // [NDIM][KDIM]
    u16* __restrict__ C) {       // [B_ROWS][NDIM] bf16
  __shared__ u16 LA[2][16384];   // [slot][piece*4096], piece = [64][64]
  __shared__ u16 LB[2][16384];

  const int tid  = threadIdx.x;
  const int lane = tid & 63;
  const int wave = tid >> 6;
  const int wm   = wave >> 2;    // 0..1
  const int wn   = wave & 3;     // 0..3
  const int r    = lane & 15;
  const int g    = lane >> 4;    // 0..3

  // col-fast XCD walk: XCD owns 8 m-panels; n-panel is the fast index.
  const int bid = blockIdx.x;
  const int xcd = bid & 7;
  const int k_  = bid >> 3;            // 0..127
  const int row0 = (xcd * 8 + (k_ >> 4)) * 256;
  const int col0 = (k_ & 15) * 256;

  // stage addressing: thread fills phys chunk tid of a piece; fetches
  // logical chunk l = tid ^ ((tid>>3)&7): row l>>3, k-chunk l&7.
  const int l    = tid ^ ((tid >> 3) & 7);
  const int srow = l >> 3;
  const int skc  = (l & 7) * 8;
  const u16* pA = A  + (size_t)(row0 + srow) * KDIM + skc;
  const u16* pB = Bw + (size_t)(col0 + srow) * KDIM + skc;

  // read addressing (u16 units): frag(m,ks) in piece (wm*2 + (m>>2)):
  //   off = piece*4096 + (m&3)*1024 + r*64 + ((ks*4+g)^(r&7))*8
  const int rx   = r & 7;
  const int kk0  = ((g      ) ^ rx) << 3;
  const int kk1  = (((4 | g)) ^ rx) << 3;
  const int abase = wm * 8192 + r * 64;
  const int bbase = wn * 4096 + r * 64;

  f32x4 acc[8][4] = {};
  bf16x8 a[4][2], b0[2][2], b1[2][2];

  // ---- prologue: tile0 full (8 pieces) + tile1 partial (A0,2 + B all) ----
  STA(0, 0, 0); STA(0, 1, 0); STA(0, 2, 0); STA(0, 3, 0);
  STB(0, 0, 0); STB(0, 1, 0); STB(0, 2, 0); STB(0, 3, 0);
  STA(1, 0, 1); STA(1, 2, 1);
  STB(1, 0, 1); STB(1, 1, 1); STB(1, 2, 1); STB(1, 3, 1);
  asm volatile("s_waitcnt vmcnt(6)" ::: "memory");  // tile0 landed
  __builtin_amdgcn_s_barrier();

  for (int it = 0; it < 16; ++it) {
    const int u = 2 * it;          // tile u -> slot 0, tile v=u+1 -> slot 1
    const bool st = it < 15;

    // p1: read A-u mb0 (8) + B-u n01 (4); stage A-v pieces 1,3
    RDA(0, 0); RDB(0, b0, 0);
    STA(1, 1, u + 1); STA(1, 3, u + 1);
    asm volatile("s_waitcnt lgkmcnt(8)" ::: "memory");
    HEAD; MQ(0, 0, b0); TAIL;

    // p2: read B-u n23 (4); stage A-u' 0,2
    RDB(0, b1, 2);
    if (st) { STA(0, 0, u + 2); STA(0, 2, u + 2); }
    HEAD; MQ(0, 2, b1); TAIL;

    // p3: read A-u mb4 (8); stage B-u' 0,1
    RDA(0, 4);
    if (st) { STB(0, 0, u + 2); STB(0, 1, u + 2); }
    HEAD; MQ(4, 0, b0); TAIL;

    // p4: stage B-u' 2,3; vmcnt(4) -> tile v fully resident
    if (st) { STB(0, 2, u + 2); STB(0, 3, u + 2); }
    HEAD; MQ(4, 2, b1);
    __builtin_amdgcn_s_setprio(0);
    __builtin_amdgcn_sched_barrier(0);
    if (st) { asm volatile("s_waitcnt vmcnt(4)" ::: "memory"); }
    else    { asm volatile("s_waitcnt vmcnt(0)" ::: "memory"); }
    __builtin_amdgcn_s_barrier();

    // p5: read A-v mb0 (8) + B-v n01 (4); stage A-u' 1,3
    RDA(1, 0); RDB(1, b0, 0);
    if (st) { STA(0, 1, u + 2); STA(0, 3, u + 2); }
    asm volatile("s_waitcnt lgkmcnt(8)" ::: "memory");
    HEAD; MQ(0, 0, b0); TAIL;

    // p6: read B-v n23 (4); stage A-v' 0,2
    RDB(1, b1, 2);
    if (st) { STA(1, 0, u + 3); STA(1, 2, u + 3); }
    HEAD; MQ(0, 2, b1); TAIL;

    // p7: read A-v mb4 (8); stage B-v' 0,1
    RDA(1, 4);
    if (st) { STB(1, 0, u + 3); STB(1, 1, u + 3); }
    HEAD; MQ(4, 0, b0); TAIL;

    // p8: stage B-v' 2,3; vmcnt(6) -> tile u' fully resident
    if (st) { STB(1, 2, u + 3); STB(1, 3, u + 3); }
    HEAD; MQ(4, 2, b1);
    __builtin_amdgcn_s_setprio(0);
    __builtin_amdgcn_sched_barrier(0);
    if (st) { asm volatile("s_waitcnt vmcnt(6)" ::: "memory"); }
    __builtin_amdgcn_s_barrier();
  }

  // ---- epilogue: C/D layout col=lane&15, row=(lane>>4)*4+reg ----
#pragma unroll
  for (int m = 0; m < 8; ++m)
#pragma unroll
    for (int n = 0; n < 4; ++n)
#pragma unroll
      for (int q = 0; q < 4; ++q) {
        const int rr = row0 + wm * 128 + m * 16 + g * 4 + q;
        const int cc = col0 + wn * 64 + n * 16 + r;
        C[(size_t)rr * NDIM + cc] = f2bf(acc[m][n][q]);
      }
}

// ---------------- LN over 4096 + gates + LSTM update ----------------
__global__ __launch_bounds__(256) void ln_gates(
    const u16* __restrict__ t,       // [B_ROWS][NDIM] bf16
    const float* __restrict__ cell,  // [B_ROWS][H]
    const float* __restrict__ gamma, // [4][H]
    const float* __restrict__ beta,  // [4][H]
    float* __restrict__ out) {       // new_out | new_cell
  const int b   = blockIdx.x;
  const int tid = threadIdx.x;
  const int h0  = tid * 4;

  const u16* trow = t + (long)b * NDIM;
  float v[4][4];
#pragma unroll
  for (int gi = 0; gi < 4; ++gi) {
    u16x4 raw = *(const u16x4*)&trow[gi * H_DIM + h0];
#pragma unroll
    for (int j = 0; j < 4; ++j) v[gi][j] = bf2f(raw[j]);
  }

  float s1 = 0.f, s2 = 0.f;
#pragma unroll
  for (int gi = 0; gi < 4; ++gi)
#pragma unroll
    for (int j = 0; j < 4; ++j) { s1 += v[gi][j]; s2 += v[gi][j] * v[gi][j]; }

#pragma unroll
  for (int m = 32; m; m >>= 1) {
    s1 += __shfl_xor(s1, m);
    s2 += __shfl_xor(s2, m);
  }
  __shared__ float red[2][4];
  const int wave = tid >> 6, lane = tid & 63;
  if (lane == 0) { red[0][wave] = s1; red[1][wave] = s2; }
  __syncthreads();
  s1 = red[0][0] + red[0][1] + red[0][2] + red[0][3];
  s2 = red[1][0] + red[1][1] + red[1][2] + red[1][3];

  const float mean  = s1 * (1.f / (float)NDIM);
  const float var   = s2 * (1.f / (float)NDIM) - mean * mean;
  const float scale = rsqrtf(var + LN_EPSF);

  float hd[4][4];
#pragma unroll
  for (int gi = 0; gi < 4; ++gi) {
    fv4 gm = *(const fv4*)&gamma[gi * H_DIM + h0];
    fv4 bt = *(const fv4*)&beta[gi * H_DIM + h0];
#pragma unroll
    for (int j = 0; j < 4; ++j)
      hd[gi][j] = (v[gi][j] - mean) * scale * gm[j] + bt[j];
  }

  fv4 cv = *(const fv4*)&cell[(long)b * H_DIM + h0];
  fv4 no, nc;
#pragma unroll
  for (int j = 0; j < 4; ++j) {
    float fg = 1.f / (1.f + expf(-hd[0][j]));
    float ig = 1.f / (1.f + expf(-hd[1][j]));
    float og = 1.f / (1.f + expf(-hd[2][j]));
    float hc = 0.5f * hd[3][j] * (1.f + erff(hd[3][j] * 0.70710678118654752f));
    float ncell = fg * cv[j] + ig * hc;
    nc[j] = ncell;
    no[j] = og * ncell;
  }
  *(fv4*)&out[(long)b * H_DIM + h0] = no;
  *(fv4*)&out[(long)B_ROWS * H_DIM + (long)b * H_DIM + h0] = nc;
}

// ---------------- launch ----------------
extern "C" void kernel_launch(void* const* d_in, const int* in_sizes, int n_in,
                              void* d_out, int out_size, void* d_ws, size_t ws_size,
                              hipStream_t stream) {
  const float* x     = (const float*)d_in[0];
  const float* h     = (const float*)d_in[1];
  const float* cell  = (const float*)d_in[2];
  const float* W     = (const float*)d_in[3];
  const float* gamma = (const float*)d_in[4];
  const float* beta  = (const float*)d_in[5];
  float* out = (float*)d_out;

  const size_t cat_bytes = (size_t)B_ROWS * KDIM * sizeof(u16);  // 64 MB
  const size_t w_bytes   = (size_t)NDIM * KDIM * sizeof(u16);    // 16 MB
  const size_t t_bytes   = (size_t)B_ROWS * NDIM * sizeof(u16);  // 128 MB
  if (ws_size < cat_bytes + w_bytes + t_bytes) return;

  uint8_t* ws = (uint8_t*)d_ws;
  u16* catb = (u16*)ws;
  u16* Wb   = (u16*)(ws + cat_bytes);
  u16* tbuf = (u16*)(ws + cat_bytes + w_bytes);

  cast_concat<<<(B_ROWS * (long)KDIM / 8) / 256, 256, 0, stream>>>(x, h, catb);
  cast_plain<<<(NDIM * (long)KDIM / 8) / 256, 256, 0, stream>>>(W, Wb);

  gemm_bt<<<dim3(1024), 512, 0, stream>>>(catb, Wb, tbuf);

  ln_gates<<<B_ROWS, 256, 0, stream>>>(tbuf, cell, gamma, beta, out);
}